// Round 1
// baseline (508.596 us; speedup 1.0000x reference)
//
#include <hip/hip_runtime.h>
#include <math.h>
#include <string.h>

#define NW 17536
#define NT 16
#define HPAD 68
#define XPAD 124

struct W3JPack { float w[363]; };

enum : int {
  O1 = 0,    // (0,0,0)  1
  O2 = 1,    // (1,1,0)  9
  O3 = 10,   // (2,2,0)  25
  O4 = 35,   // (0,1,1)  9
  O5 = 44,   // (1,0,1)  9
  O6 = 53,   // (1,2,1)  45
  O7 = 98,   // (2,1,1)  45
  O8 = 143,  // (0,2,2)  25
  O9 = 168,  // (1,1,2)  45
  O10 = 213, // (2,0,2)  25
  O11 = 238  // (2,2,2)  125
};

// ---------------- host-side Wigner 3j (exact port of reference) ----------------
static double factd(int x){ double r=1; for(int i=2;i<=x;++i) r*=(double)i; return r; }

struct UMat { double re[25]; double im[25]; };

static UMat u_real_h(int l){
  UMat U; memset(&U,0,sizeof(U));
  int d=2*l+1;
  double s = 1.0/sqrt(2.0);
  U.re[l*d+l]=1.0;
  for (int m=1;m<=l;++m){
    double sgn=(m&1)?-1.0:1.0;
    U.re[(l+m)*d + (l+m)] = sgn*s;
    U.re[(l+m)*d + (l-m)] = s;
    U.im[(l-m)*d + (l-m)] = s;
    U.im[(l-m)*d + (l+m)] = -sgn*s;
  }
  return U;
}

static void w3j_real_fill(int l1,int l2,int l3, float* out){
  int d1=2*l1+1,d2=2*l2+1,d3=2*l3+1;
  double Wc[125];
  for (int a=0;a<d1*d2*d3;++a) Wc[a]=0;
  double tri = factd(l1+l2-l3)*factd(l1-l2+l3)*factd(-l1+l2+l3)/factd(l1+l2+l3+1);
  for (int m1=-l1;m1<=l1;++m1) for (int m2=-l2;m2<=l2;++m2){
    int m3=-m1-m2;
    if (m3<-l3||m3>l3) continue;
    double pref = sqrt(tri*factd(l1+m1)*factd(l1-m1)*factd(l2+m2)*factd(l2-m2)*factd(l3+m3)*factd(l3-m3));
    int t0=0;
    if (l2-l3-m1>t0) t0=l2-l3-m1;
    if (l1-l3+m2>t0) t0=l1-l3+m2;
    int t1=l1+l2-l3;
    if (l1-m1<t1) t1=l1-m1;
    if (l2+m2<t1) t1=l2+m2;
    double s=0;
    for (int t=t0;t<=t1;++t){
      double den = factd(t)*factd(l1+l2-l3-t)*factd(l1-m1-t)*factd(l2+m2-t)
                 * factd(l3-l2+m1+t)*factd(l3-l1-m2+t);
      s += ((t&1)?-1.0:1.0)/den;
    }
    double sgn = ((l1-l2-m3)&1)?-1.0:1.0;
    Wc[(m1+l1)*d2*d3 + (m2+l2)*d3 + (m3+l3)] = sgn*pref*s;
  }
  UMat U1=u_real_h(l1), U2=u_real_h(l2), U3=u_real_h(l3);
  for (int i=0;i<d1;++i) for (int j=0;j<d2;++j) for (int k=0;k<d3;++k){
    double re=0;
    for (int m=0;m<d1;++m){
      double ar=U1.re[i*d1+m], ai=U1.im[i*d1+m];
      if (ar==0.0&&ai==0.0) continue;
      for (int nn=0;nn<d2;++nn){
        double br=U2.re[j*d2+nn], bi=U2.im[j*d2+nn];
        if (br==0.0&&bi==0.0) continue;
        double abr=ar*br-ai*bi, abi=ar*bi+ai*br;
        for (int pp=0;pp<d3;++pp){
          double w=Wc[m*d2*d3+nn*d3+pp];
          if (w==0.0) continue;
          double cr=U3.re[k*d3+pp], ci=U3.im[k*d3+pp];
          re += (abr*cr-abi*ci)*w;
        }
      }
    }
    out[(i*d2+j)*d3+k]=(float)re;
  }
}

static void build_w3j_pack(W3JPack& p){
  w3j_real_fill(0,0,0, p.w+O1);
  w3j_real_fill(1,1,0, p.w+O2);
  w3j_real_fill(2,2,0, p.w+O3);
  w3j_real_fill(0,1,1, p.w+O4);
  w3j_real_fill(1,0,1, p.w+O5);
  w3j_real_fill(1,2,1, p.w+O6);
  w3j_real_fill(2,1,1, p.w+O7);
  w3j_real_fill(0,2,2, p.w+O8);
  w3j_real_fill(1,1,2, p.w+O9);
  w3j_real_fill(2,0,2, p.w+O10);
  w3j_real_fill(2,2,2, p.w+O11);
}

// ---------------- kernel 1: per-node MLPs -> Hw[n,64], biasN[n,336] ----------------
__global__ __launch_bounds__(128) void mlp_bias_kernel(
    const float* __restrict__ ne,
    const float* __restrict__ w1w, const float* __restrict__ b1w,
    const float* __restrict__ w1b, const float* __restrict__ b1b,
    const float* __restrict__ w2b, const float* __restrict__ b2b,
    float* __restrict__ Hw, float* __restrict__ biasN, int n)
{
  int node = blockIdx.x;
  if (node >= n) return;
  int t = threadIdx.x;
  __shared__ float ne_s[128];
  __shared__ float hb_s[64];
  ne_s[t] = ne[(size_t)node*128 + t];
  __syncthreads();
  if (t < 64) {
    float acc = b1w[t];
    #pragma unroll 8
    for (int c=0;c<128;++c) acc += ne_s[c]*w1w[c*64+t];
    Hw[(size_t)node*64+t] = acc / (1.0f + expf(-acc));
  } else {
    int o = t - 64;
    float acc = b1b[o];
    #pragma unroll 8
    for (int c=0;c<128;++c) acc += ne_s[c]*w1b[c*64+o];
    hb_s[o] = acc / (1.0f + expf(-acc));
  }
  __syncthreads();
  for (int o = t; o < 336; o += 128) {
    float acc = b2b[o];
    #pragma unroll 8
    for (int c=0;c<64;++c) acc += hb_s[c]*w2b[c*336+o];
    biasN[(size_t)node*336+o] = acc;
  }
}

// ---------------- fused weight-GEMM + tensor product ----------------
template<int MULIN,int MUL1,int MUL2,int LI,int D1,int D2,int TN,bool HASB>
__device__ __forceinline__ void run_path(
    const float* __restrict__ W2, const float* __restrict__ b2w,
    const float* __restrict__ biasN,
    const float* hb, const float* xb,
    const float* w3, int u, int v, int nodebase,
    int WOFF, int XOFF, int BOFF, float inv, int n_total,
    float (&outacc)[TN][D1][D2])
{
  constexpr int K = 2*LI+1;
  constexpr int TW = 4;
  constexpr int STR = MUL1*MUL2;
  float res[TN][K];
  #pragma unroll
  for (int nn=0;nn<TN;++nn)
    #pragma unroll
    for (int k=0;k<K;++k) res[nn][k]=0.f;

  const int colb = WOFF + u*MUL2 + v;
  #pragma unroll 1
  for (int wb=0; wb<MULIN; wb+=TW) {
    float acc[TW][TN];
    #pragma unroll
    for (int t=0;t<TW;++t)
      #pragma unroll
      for (int nn=0;nn<TN;++nn) acc[t][nn]=0.f;
    const int col0 = colb + wb*STR;
    #pragma unroll 4
    for (int c=0;c<64;++c) {
      const float* r = W2 + c*NW + col0;
      float wv[TW];
      #pragma unroll
      for (int t=0;t<TW;++t) wv[t]=r[t*STR];
      #pragma unroll
      for (int nn=0;nn<TN;++nn) {
        float hv = hb[nn*HPAD+c];
        #pragma unroll
        for (int t=0;t<TW;++t) acc[t][nn] += wv[t]*hv;
      }
    }
    #pragma unroll
    for (int t=0;t<TW;++t) {
      float bw = b2w[col0 + t*STR];
      #pragma unroll
      for (int nn=0;nn<TN;++nn) {
        float wt = acc[t][nn] + bw;
        #pragma unroll
        for (int k=0;k<K;++k)
          res[nn][k] += wt * xb[nn*XPAD + XOFF + (wb+t)*K + k];
      }
    }
  }
  if (HASB) {
    #pragma unroll
    for (int nn=0;nn<TN;++nn)
      if (nodebase+nn < n_total)
        res[nn][0] += biasN[(size_t)(nodebase+nn)*336 + BOFF + u*MUL2 + v];
  }
  #pragma unroll
  for (int nn=0;nn<TN;++nn)
    #pragma unroll
    for (int i=0;i<D1;++i)
      #pragma unroll
      for (int j=0;j<D2;++j) {
        float s=0.f;
        #pragma unroll
        for (int k=0;k<K;++k) s += w3[(i*D2+j)*K+k]*res[nn][k];
        outacc[nn][i][j] += s*inv;
      }
}

template<int TN,int D1,int D2>
__device__ __forceinline__ void store_out(float* __restrict__ out, int n_total,
    int nodebase, int u, int v, int ROFF, int COFF, const float (&oa)[TN][D1][D2])
{
  #pragma unroll
  for (int nn=0;nn<TN;++nn) {
    int node = nodebase+nn;
    if (node >= n_total) continue;
    size_t base = (size_t)node*3600;
    #pragma unroll
    for (int i=0;i<D1;++i)
      #pragma unroll
      for (int j=0;j<D2;++j)
        out[base + (size_t)(ROFF+u*D1+i)*60 + (COFF+v*D2+j)] = oa[nn][i][j];
  }
}

__global__ __launch_bounds__(256) void fused_tp_kernel(
    const float* __restrict__ x_in, const float* __restrict__ Hw,
    const float* __restrict__ biasN, const float* __restrict__ W2,
    const float* __restrict__ b2w, float* __restrict__ out,
    int n, W3JPack pack)
{
  __shared__ float h_lds[NT*HPAD];
  __shared__ float x_lds[NT*XPAD];
  const int nb = blockIdx.x * NT;
  const int tid = threadIdx.x;
  for (int idx=tid; idx<NT*64; idx+=256) {
    int nn=idx>>6, c=idx&63;
    int node=nb+nn;
    h_lds[nn*HPAD+c] = (node<n)? Hw[(size_t)node*64+c] : 0.f;
  }
  for (int idx=tid; idx<NT*120; idx+=256) {
    int nn=idx/120, d=idx%120;
    int node=nb+nn;
    x_lds[nn*XPAD+d] = (node<n)? x_in[(size_t)node*120+d] : 0.f;
  }
  __syncthreads();

  // T00: path (0,0,0): mul(32,16,16) l=(0:0,0)
  {
    constexpr int P=256, TN=NT*P/256;
    const int pair=tid%P, g=tid/P;
    const int u=pair/16, v=pair%16;
    const float* hb=h_lds+g*TN*HPAD; const float* xb=x_lds+g*TN*XPAD;
    const int nbase=nb+g*TN;
    float oa[TN][1][1]={};
    run_path<32,16,16,0,1,1,TN,true >(W2,b2w,biasN,hb,xb,pack.w+O1,u,v,nbase,    0,  0,  0,1.f/32,n,oa);
    store_out<TN,1,1>(out,n,nbase,u,v, 0, 0,oa);
  }
  // T01: path (1,0,1): mul(16,16,8) li=1 -> D(1,3)
  {
    constexpr int P=128, TN=NT*P/256;
    const int pair=tid%P, g=tid/P;
    const int u=pair/8, v=pair%8;
    const float* hb=h_lds+g*TN*HPAD; const float* xb=x_lds+g*TN*XPAD;
    const int nbase=nb+g*TN;
    float oa[TN][1][3]={};
    run_path<16,16,8,1,1,3,TN,false>(W2,b2w,biasN,hb,xb,pack.w+O4,u,v,nbase,10752, 32,  0,1.f/16,n,oa);
    store_out<TN,1,3>(out,n,nbase,u,v, 0,16,oa);
  }
  // T02: path (2,0,2): mul(8,16,4) li=2 -> D(1,5)
  {
    constexpr int P=64, TN=NT*P/256;
    const int pair=tid%P, g=tid/P;
    const int u=pair/4, v=pair%4;
    const float* hb=h_lds+g*TN*HPAD; const float* xb=x_lds+g*TN*XPAD;
    const int nbase=nb+g*TN;
    float oa[TN][1][5]={};
    run_path<8,16,4,2,1,5,TN,false>(W2,b2w,biasN,hb,xb,pack.w+O8,u,v,nbase,15872, 80,  0,1.f/8 ,n,oa);
    store_out<TN,1,5>(out,n,nbase,u,v, 0,40,oa);
  }
  // T10: path (1,1,0): mul(16,8,16) li=1 -> D(3,1)
  {
    constexpr int P=128, TN=NT*P/256;
    const int pair=tid%P, g=tid/P;
    const int u=pair/16, v=pair%16;
    const float* hb=h_lds+g*TN*HPAD; const float* xb=x_lds+g*TN*XPAD;
    const int nbase=nb+g*TN;
    float oa[TN][3][1]={};
    run_path<16,8,16,1,3,1,TN,false>(W2,b2w,biasN,hb,xb,pack.w+O5,u,v,nbase,12800, 32,  0,1.f/16,n,oa);
    store_out<TN,3,1>(out,n,nbase,u,v,16, 0,oa);
  }
  // T11: paths (0,1,1) mul(32,8,8) + (2,1,1) mul(8,8,8) -> D(3,3)
  {
    constexpr int P=64, TN=NT*P/256;
    const int pair=tid%P, g=tid/P;
    const int u=pair/8, v=pair%8;
    const float* hb=h_lds+g*TN*HPAD; const float* xb=x_lds+g*TN*XPAD;
    const int nbase=nb+g*TN;
    float oa[TN][3][3]={};
    run_path<32,8,8,0,3,3,TN,true >(W2,b2w,biasN,hb,xb,pack.w+O2,u,v,nbase, 8192,  0,256,1.f/32,n,oa);
    run_path< 8,8,8,2,3,3,TN,false>(W2,b2w,biasN,hb,xb,pack.w+O9,u,v,nbase,16384, 80,  0,1.f/8 ,n,oa);
    store_out<TN,3,3>(out,n,nbase,u,v,16,16,oa);
  }
  // T12: path (1,1,2): mul(16,8,4) li=1 -> D(3,5)
  {
    constexpr int P=32, TN=NT*P/256;
    const int pair=tid%P, g=tid/P;
    const int u=pair/4, v=pair%4;
    const float* hb=h_lds+g*TN*HPAD; const float* xb=x_lds+g*TN*XPAD;
    const int nbase=nb+g*TN;
    float oa[TN][3][5]={};
    run_path<16,8,4,1,3,5,TN,false>(W2,b2w,biasN,hb,xb,pack.w+O6,u,v,nbase,14848, 32,  0,1.f/16,n,oa);
    store_out<TN,3,5>(out,n,nbase,u,v,16,40,oa);
  }
  // T20: path (2,2,0): mul(8,4,16) li=2 -> D(5,1)
  {
    constexpr int P=64, TN=NT*P/256;
    const int pair=tid%P, g=tid/P;
    const int u=pair/16, v=pair%16;
    const float* hb=h_lds+g*TN*HPAD; const float* xb=x_lds+g*TN*XPAD;
    const int nbase=nb+g*TN;
    float oa[TN][5][1]={};
    run_path<8,4,16,2,5,1,TN,false>(W2,b2w,biasN,hb,xb,pack.w+O10,u,v,nbase,16896, 80,  0,1.f/8 ,n,oa);
    store_out<TN,5,1>(out,n,nbase,u,v,40, 0,oa);
  }
  // T21: path (1,2,1): mul(16,4,8) li=1 -> D(5,3)
  {
    constexpr int P=32, TN=NT*P/256;
    const int pair=tid%P, g=tid/P;
    const int u=pair/8, v=pair%8;
    const float* hb=h_lds+g*TN*HPAD; const float* xb=x_lds+g*TN*XPAD;
    const int nbase=nb+g*TN;
    float oa[TN][5][3]={};
    run_path<16,4,8,1,5,3,TN,false>(W2,b2w,biasN,hb,xb,pack.w+O7,u,v,nbase,15360, 32,  0,1.f/16,n,oa);
    store_out<TN,5,3>(out,n,nbase,u,v,40,16,oa);
  }
  // T22: paths (0,2,2) mul(32,4,4) + (2,2,2) mul(8,4,4) -> D(5,5)
  {
    constexpr int P=16, TN=NT*P/256;
    const int pair=tid%P, g=tid/P;
    const int u=pair/4, v=pair%4;
    const float* hb=h_lds+g*TN*HPAD; const float* xb=x_lds+g*TN*XPAD;
    const int nbase=nb+g*TN;
    float oa[TN][5][5]={};
    run_path<32,4,4,0,5,5,TN,true >(W2,b2w,biasN,hb,xb,pack.w+O3 ,u,v,nbase,10240,  0,320,1.f/32,n,oa);
    run_path< 8,4,4,2,5,5,TN,false>(W2,b2w,biasN,hb,xb,pack.w+O11,u,v,nbase,17408, 80,  0,1.f/8 ,n,oa);
    store_out<TN,5,5>(out,n,nbase,u,v,40,40,oa);
  }
}

// ---------------- launch ----------------
extern "C" void kernel_launch(void* const* d_in, const int* in_sizes, int n_in,
                              void* d_out, int out_size, void* d_ws, size_t ws_size,
                              hipStream_t stream)
{
  const float* x_in = (const float*)d_in[0];
  const float* ne   = (const float*)d_in[1];
  const float* w1w  = (const float*)d_in[2];
  const float* b1w  = (const float*)d_in[3];
  const float* w2w  = (const float*)d_in[4];
  const float* b2w  = (const float*)d_in[5];
  const float* w1b  = (const float*)d_in[6];
  const float* b1b  = (const float*)d_in[7];
  const float* w2b  = (const float*)d_in[8];
  const float* b2b  = (const float*)d_in[9];
  float* out = (float*)d_out;
  const int n = in_sizes[0] / 120;

  float* Hw = (float*)d_ws;                 // n*64 floats
  float* biasN = Hw + (size_t)n*64;         // n*336 floats

  W3JPack pack;
  build_w3j_pack(pack);

  mlp_bias_kernel<<<n, 128, 0, stream>>>(ne, w1w, b1w, w1b, b1b, w2b, b2b, Hw, biasN, n);
  const int nblk = (n + NT - 1) / NT;
  fused_tp_kernel<<<nblk, 256, 0, stream>>>(x_in, Hw, biasN, w2w, b2w, out, n, pack);
}